// Round 3
// baseline (279.562 us; speedup 1.0000x reference)
//
#include <hip/hip_runtime.h>
#include <hip/hip_fp16.h>

#define HDIM 256
#define MS 16

typedef _Float16 half8 __attribute__((ext_vector_type(8)));
typedef _Float16 half4 __attribute__((ext_vector_type(4)));
typedef float f32x4 __attribute__((ext_vector_type(4)));

__device__ __forceinline__ float fast_tanh(float x) {
    // tanh(x) = 1 - 2/(e^{2x}+1); v_exp-based, graceful at +-inf
    float e = __expf(2.0f * x);
    return 1.0f - 2.0f * __builtin_amdgcn_rcpf(e + 1.0f);
}

// Swizzled column (in halves): XOR the 16B-group index (bits 3..5) with row low-3.
// Row stride is exactly 256 halves (512 B, bank-aligned); the XOR spreads each
// b128 read / b64 write across all 32 banks.
__device__ __forceinline__ int swz(int row, int col) {
    return (col & 0xC7) | (((((col >> 3) ^ row)) & 7) << 3);
}

// Pack W1,W2,W3 (fp32 [256][256], row=k, col=n) into f16 frag layout:
// Wp[l][ ((k>>3)*256 + n)*8 + (k&7) ].  Thread owns 8 k for one n:
// coalesced fp32 reads (lane-contiguous n), one coalesced 16B write.
__global__ __launch_bounds__(256) void pack_weights(const float* __restrict__ W1,
                                                    const float* __restrict__ W2,
                                                    const float* __restrict__ W3,
                                                    _Float16* __restrict__ out) {
    int tid = blockIdx.x * 256 + threadIdx.x;  // 0..24575
    int l = tid >> 13;
    int idx = tid & 8191;   // kg*256 + n
    int kg = idx >> 8;
    int n = idx & 255;
    const float* W = (l == 0) ? W1 : (l == 1) ? W2 : W3;
    half8 v;
    #pragma unroll
    for (int j = 0; j < 8; ++j) v[j] = (_Float16)W[(kg * 8 + j) * 256 + n];
    *(half8*)(out + l * 65536 + (kg * 256 + n) * 8) = v;
}

__global__ __launch_bounds__(512, 4)
void pinn_fused(const float* __restrict__ x,
                const float* __restrict__ W0,
                const float* __restrict__ b0,
                const float* __restrict__ b1,
                const float* __restrict__ b2,
                const float* __restrict__ b3,
                const float* __restrict__ Wout,
                const float* __restrict__ bout,
                const _Float16* __restrict__ Wp,
                float* __restrict__ out) {
    // A: stacked [7 channels x 16 samples] rows x 256 k, f16, swizzled, no pad
    __shared__ __align__(16) _Float16 Abuf[7 * MS * HDIM];  // 56 KB
    __shared__ float xs[MS * 3];

    const int tid  = threadIdx.x;
    const int lane = tid & 63;
    const int wid  = tid >> 6;        // wave id 0..7 -> n-strip base wid*32
    const int qd   = lane >> 4;       // quad 0..3
    const int n15  = lane & 15;
    const int base = blockIdx.x * MS; // sample base

    if (tid < MS * 3) xs[tid] = x[base * 3 + tid];
    __syncthreads();

    // ---------------- layer 0: 3 -> 256, jets analytic; one half8 per channel ----------------
    {
        const int m  = tid & 15;
        const int n0 = (tid >> 4) * 8;    // 8 consecutive n per thread
        const float x0 = xs[m * 3 + 0], x1 = xs[m * 3 + 1], x2 = xs[m * 3 + 2];
        half8 h[7];
        #pragma unroll
        for (int r = 0; r < 8; ++r) {
            const int n = n0 + r;
            const float w0 = W0[n], w1 = W0[HDIM + n], w2 = W0[2 * HDIM + n];
            float z  = x0 * w0 + x1 * w1 + x2 * w2 + b0[n];
            float tv = fast_tanh(z);
            float dd = 1.f - tv * tv;
            float c2 = -2.f * tv * dd;
            h[0][r] = (_Float16)tv;
            h[1][r] = (_Float16)(dd * w0);
            h[2][r] = (_Float16)(dd * w1);
            h[3][r] = (_Float16)(dd * w2);
            h[4][r] = (_Float16)(c2 * w0 * w0);
            h[5][r] = (_Float16)(c2 * w1 * w1);
            h[6][r] = (_Float16)(c2 * w2 * w2);
        }
        #pragma unroll
        for (int c = 0; c < 7; ++c) {
            const int row = c * MS + m;
            *(half8*)&Abuf[row * HDIM + swz(row, n0)] = h[c];
        }
    }
    __syncthreads();

    // ---------------- layers 1..3: transposed MFMA (Z^T = W^T A^T) ----------------
    #pragma unroll
    for (int l = 0; l < 3; ++l) {
        const _Float16* W = Wp + l * 65536;
        const float* bb = (l == 0) ? b1 : (l == 1) ? b2 : b3;

        f32x4 acc[7][2];
        #pragma unroll
        for (int c = 0; c < 7; ++c)
            #pragma unroll
            for (int t = 0; t < 2; ++t) acc[c][t] = (f32x4){0.f, 0.f, 0.f, 0.f};

        #pragma unroll
        for (int s = 0; s < 8; ++s) {
            half8 wf[2];
            #pragma unroll
            for (int t = 0; t < 2; ++t) {
                const int n = wid * 32 + t * 16 + n15;
                wf[t] = *(const half8*)(W + ((s * 4 + qd) * 256 + n) * 8);
            }
            #pragma unroll
            for (int c = 0; c < 7; ++c) {
                const int row = c * MS + n15;
                half8 af = *(const half8*)&Abuf[row * HDIM + swz(row, s * 32 + qd * 8)];
                #pragma unroll
                for (int t = 0; t < 2; ++t)
                    acc[c][t] = __builtin_amdgcn_mfma_f32_16x16x32_f16(wf[t], af, acc[c][t], 0, 0, 0);
            }
        }
        __syncthreads();  // all waves done reading Abuf

        // lane holds Z[m = n15][n = wid*32 + t*16 + qd*4 + r], r=0..3
        #pragma unroll
        for (int t = 0; t < 2; ++t) {
            const int ncol = wid * 32 + t * 16 + qd * 4;
            f32x4 bv = *(const f32x4*)(bb + ncol);
            half4 h[7];
            #pragma unroll
            for (int r = 0; r < 4; ++r) {
                float zv = acc[0][t][r] + bv[r];
                float tv = fast_tanh(zv);
                float dd = 1.f - tv * tv;
                float c2 = -2.f * tv * dd;
                h[0][r] = (_Float16)tv;
                #pragma unroll
                for (int i = 0; i < 3; ++i) {
                    float zg = acc[1 + i][t][r];
                    float zs = acc[4 + i][t][r];
                    h[1 + i][r] = (_Float16)(dd * zg);
                    h[4 + i][r] = (_Float16)(dd * zs + c2 * zg * zg);
                }
            }
            #pragma unroll
            for (int c = 0; c < 7; ++c) {
                const int row = c * MS + n15;
                *(half4*)&Abuf[row * HDIM + swz(row, ncol)] = h[c];
            }
        }
        __syncthreads();
    }

    // ---------------- output: 112 rows x 256 dot Wout; 4 threads/row, shfl-reduce ----------------
    if (tid < 7 * MS * 4) {
        const int row = tid >> 2;        // 0..111
        const int h   = tid & 3;
        float accv = 0.f;
        #pragma unroll
        for (int kg = 0; kg < 8; ++kg) {
            const int col = h * 64 + kg * 8;
            half8 av = *(const half8*)&Abuf[row * HDIM + swz(row, col)];
            f32x4 wa = *(const f32x4*)(Wout + col);
            f32x4 wb = *(const f32x4*)(Wout + col + 4);
            #pragma unroll
            for (int j = 0; j < 4; ++j) accv += (float)av[j] * wa[j];
            #pragma unroll
            for (int j = 0; j < 4; ++j) accv += (float)av[4 + j] * wb[j];
        }
        accv += __shfl_xor(accv, 1, 64);
        accv += __shfl_xor(accv, 2, 64);
        if (h == 0) {
            const int c = row >> 4;
            const int m = row & 15;
            if (c == 0) accv += bout[0];
            out[(base + m) * 7 + c] = accv;
        }
    }
}

extern "C" void kernel_launch(void* const* d_in, const int* in_sizes, int n_in,
                              void* d_out, int out_size, void* d_ws, size_t ws_size,
                              hipStream_t stream) {
    const float* xp   = (const float*)d_in[0];
    const float* W0   = (const float*)d_in[1];
    const float* b0   = (const float*)d_in[2];
    const float* W1   = (const float*)d_in[3];
    const float* b1   = (const float*)d_in[4];
    const float* W2   = (const float*)d_in[5];
    const float* b2   = (const float*)d_in[6];
    const float* W3   = (const float*)d_in[7];
    const float* b3   = (const float*)d_in[8];
    const float* Wout = (const float*)d_in[9];
    const float* bout = (const float*)d_in[10];
    _Float16* Wp = (_Float16*)d_ws;  // 3 * 65536 halves = 384 KB

    pack_weights<<<96, 256, 0, stream>>>(W1, W2, W3, Wp);
    pinn_fused<<<65536 / MS, 512, 0, stream>>>(xp, W0, b0, b1, b2, b3, Wout, bout, Wp,
                                               (float*)d_out);
}

// Round 4
// 262.580 us; speedup vs baseline: 1.0647x; 1.0647x over previous
//
#include <hip/hip_runtime.h>
#include <hip/hip_fp16.h>

#define HDIM 256
#define MS 16
#define LDAK 264   // 256 + 8 halves pad: row stride = 4 banks -> 2-way (free) aliasing

typedef _Float16 half8 __attribute__((ext_vector_type(8)));
typedef _Float16 half4 __attribute__((ext_vector_type(4)));
typedef float f32x4 __attribute__((ext_vector_type(4)));

__device__ __forceinline__ float fast_tanh(float x) {
    // tanh(x) = 1 - 2/(e^{2x}+1); v_exp-based, graceful at +-inf
    float e = __expf(2.0f * x);
    return 1.0f - 2.0f * __builtin_amdgcn_rcpf(e + 1.0f);
}

// Pack W1,W2,W3 (fp32 [256][256], row=k, col=n) into f16 frag layout:
// Wp[l][ ((k>>3)*256 + n)*8 + (k&7) ].  Thread owns 8 k for one n:
// coalesced fp32 reads, one coalesced 16B write.
__global__ __launch_bounds__(256) void pack_weights(const float* __restrict__ W1,
                                                    const float* __restrict__ W2,
                                                    const float* __restrict__ W3,
                                                    _Float16* __restrict__ out) {
    int tid = blockIdx.x * 256 + threadIdx.x;  // 0..24575
    int l = tid >> 13;
    int idx = tid & 8191;   // kg*256 + n
    int kg = idx >> 8;
    int n = idx & 255;
    const float* W = (l == 0) ? W1 : (l == 1) ? W2 : W3;
    half8 v;
    #pragma unroll
    for (int j = 0; j < 8; ++j) v[j] = (_Float16)W[(kg * 8 + j) * 256 + n];
    *(half8*)(out + l * 65536 + (kg * 256 + n) * 8) = v;
}

__global__ __launch_bounds__(256, 2)
void pinn_fused(const float* __restrict__ x,
                const float* __restrict__ W0,
                const float* __restrict__ b0,
                const float* __restrict__ b1,
                const float* __restrict__ b2,
                const float* __restrict__ b3,
                const float* __restrict__ Wout,
                const float* __restrict__ bout,
                const _Float16* __restrict__ Wp,
                float* __restrict__ out) {
    // A: stacked [7 channels x 16 samples] rows x 256 k, f16, pad-264
    __shared__ __align__(16) _Float16 Abuf[7 * MS][LDAK];
    __shared__ float xs[MS * 3];

    const int tid  = threadIdx.x;
    const int lane = tid & 63;
    const int wid  = tid >> 6;        // wave id 0..3 -> n-strip base wid*64
    const int qd   = lane >> 4;       // quad 0..3
    const int n15  = lane & 15;
    const int base = blockIdx.x * MS; // sample base

    if (tid < MS * 3) xs[tid] = x[base * 3 + tid];
    __syncthreads();

    // ---------------- layer 0: 3 -> 256, jets analytic; half8 writes ----------------
    {
        const int m  = tid & 15;
        const int nb = (tid >> 4) * 16;   // 16 consecutive n per thread, 2 half8 chunks
        const float x0 = xs[m * 3 + 0], x1 = xs[m * 3 + 1], x2 = xs[m * 3 + 2];
        #pragma unroll
        for (int ch = 0; ch < 2; ++ch) {
            const int n0 = nb + ch * 8;
            half8 h[7];
            #pragma unroll
            for (int r = 0; r < 8; ++r) {
                const int n = n0 + r;
                const float w0 = W0[n], w1 = W0[HDIM + n], w2 = W0[2 * HDIM + n];
                float z  = x0 * w0 + x1 * w1 + x2 * w2 + b0[n];
                float tv = fast_tanh(z);
                float dd = 1.f - tv * tv;
                float c2 = -2.f * tv * dd;
                h[0][r] = (_Float16)tv;
                h[1][r] = (_Float16)(dd * w0);
                h[2][r] = (_Float16)(dd * w1);
                h[3][r] = (_Float16)(dd * w2);
                h[4][r] = (_Float16)(c2 * w0 * w0);
                h[5][r] = (_Float16)(c2 * w1 * w1);
                h[6][r] = (_Float16)(c2 * w2 * w2);
            }
            #pragma unroll
            for (int c = 0; c < 7; ++c)
                *(half8*)&Abuf[c * MS + m][n0] = h[c];
        }
    }
    __syncthreads();

    // ---------------- layers 1..3: transposed MFMA, software-pipelined K ----------------
    // Persistent across layers: wf[0] holds the next layer's s=0 weight frags.
    half8 wf[2][4];
    {
        #pragma unroll
        for (int t = 0; t < 4; ++t) {
            const int n = wid * 64 + t * 16 + n15;
            wf[0][t] = *(const half8*)(Wp + (qd * 256 + n) * 8);  // layer 0 (W1), s=0
        }
    }

    #pragma unroll
    for (int l = 0; l < 3; ++l) {
        const _Float16* W  = Wp + l * 65536;
        const _Float16* Wn = Wp + (l < 2 ? l + 1 : 2) * 65536;   // l=2 dup, discarded
        const float* bb = (l == 0) ? b1 : (l == 1) ? b2 : b3;

        f32x4 acc[7][4];
        #pragma unroll
        for (int c = 0; c < 7; ++c)
            #pragma unroll
            for (int t = 0; t < 4; ++t) acc[c][t] = (f32x4){0.f, 0.f, 0.f, 0.f};

        half8 af[2][7];
        #pragma unroll
        for (int c = 0; c < 7; ++c)
            af[0][c] = *(const half8*)&Abuf[c * MS + n15][qd * 8];   // s=0

        #pragma unroll
        for (int s = 0; s < 8; ++s) {
            const int cur = s & 1, nxt = cur ^ 1;
            // prefetch s+1 (or next layer's s=0 weights at s==7) before the MFMA block
            if (s < 7) {
                #pragma unroll
                for (int t = 0; t < 4; ++t) {
                    const int n = wid * 64 + t * 16 + n15;
                    wf[nxt][t] = *(const half8*)(W + (((s + 1) * 4 + qd) * 256 + n) * 8);
                }
                #pragma unroll
                for (int c = 0; c < 7; ++c)
                    af[nxt][c] = *(const half8*)&Abuf[c * MS + n15][(s + 1) * 32 + qd * 8];
            } else {
                #pragma unroll
                for (int t = 0; t < 4; ++t) {
                    const int n = wid * 64 + t * 16 + n15;
                    wf[nxt][t] = *(const half8*)(Wn + (qd * 256 + n) * 8);
                }
            }
            #pragma unroll
            for (int c = 0; c < 7; ++c)
                #pragma unroll
                for (int t = 0; t < 4; ++t)
                    acc[c][t] = __builtin_amdgcn_mfma_f32_16x16x32_f16(wf[cur][t], af[cur][c], acc[c][t], 0, 0, 0);
        }
        __syncthreads();  // all waves done reading Abuf

        // lane holds Z[m = n15][n = wid*64 + t*16 + qd*4 + r], r=0..3
        #pragma unroll
        for (int t = 0; t < 4; ++t) {
            const int ncol = wid * 64 + t * 16 + qd * 4;
            f32x4 bv = *(const f32x4*)(bb + ncol);
            half4 h[7];
            #pragma unroll
            for (int r = 0; r < 4; ++r) {
                float zv = acc[0][t][r] + bv[r];
                float tv = fast_tanh(zv);
                float dd = 1.f - tv * tv;
                float c2 = -2.f * tv * dd;
                h[0][r] = (_Float16)tv;
                #pragma unroll
                for (int i = 0; i < 3; ++i) {
                    float zg = acc[1 + i][t][r];
                    float zs = acc[4 + i][t][r];
                    h[1 + i][r] = (_Float16)(dd * zg);
                    h[4 + i][r] = (_Float16)(dd * zs + c2 * zg * zg);
                }
            }
            #pragma unroll
            for (int c = 0; c < 7; ++c)
                *(half4*)&Abuf[c * MS + n15][ncol] = h[c];
        }
        __syncthreads();
    }

    // ---------------- output: 112 rows x 256 dot Wout; 2 threads/row, pair-reduce ----------------
    if (tid < 7 * MS * 2) {
        const int row = tid >> 1;        // 0..111
        const int h   = tid & 1;
        const _Float16* rp = &Abuf[row][h * 128];
        const float* wp = Wout + h * 128;
        float accv = 0.f;
        #pragma unroll 4
        for (int k = 0; k < 128; k += 8) {
            half8 av = *(const half8*)&rp[k];
            #pragma unroll
            for (int j = 0; j < 8; ++j) accv += (float)av[j] * wp[k + j];
        }
        accv += __shfl_xor(accv, 1, 64);
        if (h == 0) {
            const int c = row >> 4;
            const int m = row & 15;
            if (c == 0) accv += bout[0];
            out[(base + m) * 7 + c] = accv;
        }
    }
}

extern "C" void kernel_launch(void* const* d_in, const int* in_sizes, int n_in,
                              void* d_out, int out_size, void* d_ws, size_t ws_size,
                              hipStream_t stream) {
    const float* xp   = (const float*)d_in[0];
    const float* W0   = (const float*)d_in[1];
    const float* b0   = (const float*)d_in[2];
    const float* W1   = (const float*)d_in[3];
    const float* b1   = (const float*)d_in[4];
    const float* W2   = (const float*)d_in[5];
    const float* b2   = (const float*)d_in[6];
    const float* W3   = (const float*)d_in[7];
    const float* b3   = (const float*)d_in[8];
    const float* Wout = (const float*)d_in[9];
    const float* bout = (const float*)d_in[10];
    _Float16* Wp = (_Float16*)d_ws;  // 3 * 65536 halves = 384 KB

    pack_weights<<<96, 256, 0, stream>>>(W1, W2, W3, Wp);
    pinn_fused<<<65536 / MS, 256, 0, stream>>>(xp, W0, b0, b1, b2, b3, Wout, bout, Wp,
                                               (float*)d_out);
}

// Round 6
// 255.309 us; speedup vs baseline: 1.0950x; 1.0285x over previous
//
#include <hip/hip_runtime.h>
#include <hip/hip_fp16.h>

#define HDIM 256
#define MS 16
#define LDAK 264   // 256 + 8 halves pad: row stride = 4 banks -> 2-way (free) aliasing

typedef _Float16 half8 __attribute__((ext_vector_type(8)));
typedef _Float16 half4 __attribute__((ext_vector_type(4)));
typedef _Float16 half2v __attribute__((ext_vector_type(2)));
typedef float f32x4 __attribute__((ext_vector_type(4)));

__device__ __forceinline__ float fast_tanh(float x) {
    // tanh(x) = 1 - 2/(e^{2x}+1); v_exp-based, graceful at +-inf
    float e = __expf(2.0f * x);
    return 1.0f - 2.0f * __builtin_amdgcn_rcpf(e + 1.0f);
}

__device__ __forceinline__ half4 cvt4(float a, float b, float c, float d) {
    half2v lo = __builtin_bit_cast(half2v, __builtin_amdgcn_cvt_pkrtz(a, b));
    half2v hi = __builtin_bit_cast(half2v, __builtin_amdgcn_cvt_pkrtz(c, d));
    half4 r; r[0] = lo[0]; r[1] = lo[1]; r[2] = hi[0]; r[3] = hi[1];
    return r;
}

// Pack W1,W2,W3 (fp32 [256][256], row=k, col=n) into f16 frag layout:
// Wp[l][ ((k>>3)*256 + n)*8 + (k&7) ].  Thread owns 8 k for one n:
// coalesced fp32 reads, one coalesced 16B write.
__global__ __launch_bounds__(256) void pack_weights(const float* __restrict__ W1,
                                                    const float* __restrict__ W2,
                                                    const float* __restrict__ W3,
                                                    _Float16* __restrict__ out) {
    int tid = blockIdx.x * 256 + threadIdx.x;  // 0..24575
    int l = tid >> 13;
    int idx = tid & 8191;   // kg*256 + n
    int kg = idx >> 8;
    int n = idx & 255;
    const float* W = (l == 0) ? W1 : (l == 1) ? W2 : W3;
    half8 v;
    #pragma unroll
    for (int j = 0; j < 8; ++j) v[j] = (_Float16)W[(kg * 8 + j) * 256 + n];
    *(half8*)(out + l * 65536 + (kg * 256 + n) * 8) = v;
}

__global__ __launch_bounds__(256, 2)
void pinn_fused(const float* __restrict__ x,
                const float* __restrict__ W0,
                const float* __restrict__ b0,
                const float* __restrict__ b1,
                const float* __restrict__ b2,
                const float* __restrict__ b3,
                const float* __restrict__ Wout,
                const float* __restrict__ bout,
                const _Float16* __restrict__ Wp,
                float* __restrict__ out) {
    // A: stacked [7 channels x 16 samples] rows x 256 k, f16, pad-264
    __shared__ __align__(16) _Float16 Abuf[7 * MS][LDAK];
    __shared__ float xs[MS * 3];

    const int tid  = threadIdx.x;
    const int lane = tid & 63;
    const int wid  = tid >> 6;        // wave id 0..3 -> n-strip base wid*64
    const int qd   = lane >> 4;       // quad 0..3
    const int n15  = lane & 15;
    const int base = blockIdx.x * MS; // sample base
    const int nw   = wid * 64 + n15;  // wf column base

    if (tid < MS * 3) xs[tid] = x[base * 3 + tid];

    // 3-deep W pipeline over flat step g = l*8+s (24 steps). Issue g=0,1 now so
    // the L2 reads overlap layer-0 math.
    half8 wf[3][4];
    #pragma unroll
    for (int t = 0; t < 4; ++t)
        wf[0][t] = *(const half8*)(Wp + ((0 * 4 + qd) * 256 + nw + t * 16) * 8);
    #pragma unroll
    for (int t = 0; t < 4; ++t)
        wf[1][t] = *(const half8*)(Wp + ((1 * 4 + qd) * 256 + nw + t * 16) * 8);

    __syncthreads();   // xs ready

    // ---------------- layer 0: 3 -> 256, jets analytic; half8 writes ----------------
    {
        const int m  = tid & 15;
        const int nb = (tid >> 4) * 16;   // 16 consecutive n per thread, 2 half8 chunks
        const float x0 = xs[m * 3 + 0], x1 = xs[m * 3 + 1], x2 = xs[m * 3 + 2];
        #pragma unroll
        for (int ch = 0; ch < 2; ++ch) {
            const int n0 = nb + ch * 8;
            half8 h[7];
            #pragma unroll
            for (int r = 0; r < 8; ++r) {
                const int n = n0 + r;
                const float w0 = W0[n], w1 = W0[HDIM + n], w2 = W0[2 * HDIM + n];
                float z  = x0 * w0 + x1 * w1 + x2 * w2 + b0[n];
                float tv = fast_tanh(z);
                float dd = 1.f - tv * tv;
                float c2 = -2.f * tv * dd;
                h[0][r] = (_Float16)tv;
                h[1][r] = (_Float16)(dd * w0);
                h[2][r] = (_Float16)(dd * w1);
                h[3][r] = (_Float16)(dd * w2);
                h[4][r] = (_Float16)(c2 * w0 * w0);
                h[5][r] = (_Float16)(c2 * w1 * w1);
                h[6][r] = (_Float16)(c2 * w2 * w2);
            }
            #pragma unroll
            for (int c = 0; c < 7; ++c)
                *(half8*)&Abuf[c * MS + m][n0] = h[c];
        }
    }
    __syncthreads();

    // ---------------- layers 1..3: transposed MFMA (Z^T = W^T A^T) ----------------
    #pragma unroll
    for (int l = 0; l < 3; ++l) {
        const float* bb = (l == 0) ? b1 : (l == 1) ? b2 : b3;

        f32x4 acc[7][4];
        #pragma unroll
        for (int c = 0; c < 7; ++c)
            #pragma unroll
            for (int t = 0; t < 4; ++t) acc[c][t] = (f32x4){0.f, 0.f, 0.f, 0.f};

        #pragma unroll
        for (int s = 0; s < 8; ++s) {
            const int g = l * 8 + s;
            // prefetch step g+2's weight frags (compile-time guard; crosses
            // layer boundaries and elem interludes untouched)
            if (g + 2 < 24) {
                const _Float16* Wn = Wp + ((g + 2) >> 3) * 65536;
                const int sn = (g + 2) & 7;
                #pragma unroll
                for (int t = 0; t < 4; ++t)
                    wf[(g + 2) % 3][t] =
                        *(const half8*)(Wn + ((sn * 4 + qd) * 256 + nw + t * 16) * 8);
            }
            // A-frags for this step: compiler pipelines ds_read -> MFMA via lgkmcnt
            half8 af[7];
            #pragma unroll
            for (int c = 0; c < 7; ++c)
                af[c] = *(const half8*)&Abuf[c * MS + n15][s * 32 + qd * 8];
            #pragma unroll
            for (int c = 0; c < 7; ++c)
                #pragma unroll
                for (int t = 0; t < 4; ++t)
                    acc[c][t] = __builtin_amdgcn_mfma_f32_16x16x32_f16(wf[g % 3][t], af[c], acc[c][t], 0, 0, 0);
        }
        __syncthreads();  // all waves done reading Abuf

        // lane holds Z[m = n15][n = wid*64 + t*16 + qd*4 + r], r=0..3
        #pragma unroll
        for (int t = 0; t < 4; ++t) {
            const int ncol = wid * 64 + t * 16 + qd * 4;
            f32x4 bv = *(const f32x4*)(bb + ncol);
            float tv[4], gj[3][4], sj[3][4];
            #pragma unroll
            for (int r = 0; r < 4; ++r) {
                float zv = acc[0][t][r] + bv[r];
                tv[r] = fast_tanh(zv);
                float dd = 1.f - tv[r] * tv[r];
                float c2 = -2.f * tv[r] * dd;
                #pragma unroll
                for (int i = 0; i < 3; ++i) {
                    float zg = acc[1 + i][t][r];
                    float zs = acc[4 + i][t][r];
                    gj[i][r] = dd * zg;
                    sj[i][r] = dd * zs + c2 * zg * zg;
                }
            }
            *(half4*)&Abuf[0 * MS + n15][ncol] = cvt4(tv[0], tv[1], tv[2], tv[3]);
            #pragma unroll
            for (int i = 0; i < 3; ++i) {
                *(half4*)&Abuf[(1 + i) * MS + n15][ncol] = cvt4(gj[i][0], gj[i][1], gj[i][2], gj[i][3]);
                *(half4*)&Abuf[(4 + i) * MS + n15][ncol] = cvt4(sj[i][0], sj[i][1], sj[i][2], sj[i][3]);
            }
        }
        __syncthreads();
    }

    // ---------------- output: 112 rows x 256 dot Wout; 2 threads/row, pair-reduce ----------------
    if (tid < 7 * MS * 2) {
        const int row = tid >> 1;        // 0..111
        const int h   = tid & 1;
        const _Float16* rp = &Abuf[row][h * 128];
        const float* wp = Wout + h * 128;
        float accv = 0.f;
        #pragma unroll 4
        for (int k = 0; k < 128; k += 8) {
            half8 av = *(const half8*)&rp[k];
            #pragma unroll
            for (int j = 0; j < 8; ++j) accv += (float)av[j] * wp[k + j];
        }
        accv += __shfl_xor(accv, 1, 64);
        if (h == 0) {
            const int c = row >> 4;
            const int m = row & 15;
            if (c == 0) accv += bout[0];
            out[(base + m) * 7 + c] = accv;
        }
    }
}

extern "C" void kernel_launch(void* const* d_in, const int* in_sizes, int n_in,
                              void* d_out, int out_size, void* d_ws, size_t ws_size,
                              hipStream_t stream) {
    const float* xp   = (const float*)d_in[0];
    const float* W0   = (const float*)d_in[1];
    const float* b0   = (const float*)d_in[2];
    const float* W1   = (const float*)d_in[3];
    const float* b1   = (const float*)d_in[4];
    const float* W2   = (const float*)d_in[5];
    const float* b2   = (const float*)d_in[6];
    const float* W3   = (const float*)d_in[7];
    const float* b3   = (const float*)d_in[8];
    const float* Wout = (const float*)d_in[9];
    const float* bout = (const float*)d_in[10];
    _Float16* Wp = (_Float16*)d_ws;  // 3 * 65536 halves = 384 KB

    pack_weights<<<96, 256, 0, stream>>>(W1, W2, W3, Wp);
    pinn_fused<<<65536 / MS, 256, 0, stream>>>(xp, W0, b0, b1, b2, b3, Wout, bout, Wp,
                                               (float*)d_out);
}